// Round 10
// baseline (213.513 us; speedup 1.0000x reference)
//
#include <hip/hip_runtime.h>

typedef __attribute__((ext_vector_type(8))) short s8v;
typedef __attribute__((ext_vector_type(16))) float f16vf;
typedef __attribute__((ext_vector_type(4))) unsigned int u4v;
typedef __attribute__((ext_vector_type(2))) unsigned int u2v;

static __device__ __forceinline__ unsigned short f2b(float f) {
  unsigned int u = __builtin_bit_cast(unsigned int, f);
  u += 0x7fffu + ((u >> 16) & 1u);  // RNE
  return (unsigned short)(u >> 16);
}

#if defined(__has_builtin)
#if __has_builtin(__builtin_amdgcn_cvt_pk_bf16_f32)
#define HAVE_PK_BF16 1
#endif
#endif

// pack two floats -> bf16x2 dword (lo = a, hi = b)
static __device__ __forceinline__ unsigned int pk2(float a, float b) {
#ifdef HAVE_PK_BF16
  auto r = __builtin_amdgcn_cvt_pk_bf16_f32(a, b);
  static_assert(sizeof(r) == 4, "pk bf16 size");
  return __builtin_bit_cast(unsigned int, r);
#else
  return (unsigned int)f2b(a) | ((unsigned int)f2b(b) << 16);
#endif
}

// ---- FUSED attention: packs raw fp32 K/V into LDS itself -------------------
// R9 post-mortem: total pinned at ~151us across 3 sessions while attn alone
// improved; prepack dispatch + 16MB ws round-trip is the ~80us residual
// suspect. This kernel removes BOTH (no prepack, no workspace).
// Staging (T14 reg-staged, per 64-key tile, per block):
//   K: row-major bf16 [64 k][128 d] with G4 XOR swizzle chunk^((row&7)<<4)
//      (write: lanes vary chunk in-row -> conflict-free; read: lanes vary
//       row -> 4-way, ~free per m136)
//   V: 4x4 register-block transpose (ported from the VERIFIED prepack) into
//      the EXACT V^T slot-major layout the PV reads already use.
// Compute body, masks, softmax, PV, epilogue: byte-identical to verified R1.
__global__ __launch_bounds__(256, 2) void gqa_attn_kernel(
    const float* __restrict__ Q, const float* __restrict__ K,
    const float* __restrict__ V, float* __restrict__ O) {
  constexpr float QS = 0.08838834764831845f * 1.4426950408889634f;  // 1/sqrt(128)*log2e
  constexpr float CREF = 12.0f;  // constant softmax reference (scores*log2e ~ +-8.5)

  // 64KB: K bf16 64-key tile bufs @ {0,16384}; V^T bufs @ 32768+{0,16384}
  __shared__ unsigned short sh[32768];
  char* shc = (char*)sh;

  const int tid = threadIdx.x;
  const int l = tid & 63, w = tid >> 6;
  const int col = l & 31, hh = l >> 5;
  const bool h1 = hh != 0;

  const int bx = blockIdx.x;
  const int bh = bx & 31;  // b*16 + h  (same-bh blocks share an XCD: L2 reuse)
  const int g = bx >> 5;
  const int qt = (g < 8) ? (15 - g) : (g - 8);  // zigzag pairing, heavy first
  const int b = bh >> 4, h = bh & 15;
  const int bk = b * 8 + (h >> 1);

  const float* Qb = Q + ((size_t)bh * 2048) * 128;
  const float* Kb = K + ((size_t)bk * 2048) * 128;
  const float* Vb = V + ((size_t)bk * 2048) * 128;
  float* Ob = O + ((size_t)bh * 2048) * 128;

  // V^T read base within a 32-key subtile (unchanged from verified R1)
  const int vVb = col * 16 + hh * 2048;
  // K swizzle term for this lane
  const int kswz = (col & 7) << 4;

  // ---- staging: load raw fp32 tile kb into regs (issue early, wait late)
  auto loadKV = [&](int kb, float4 (&ka)[4][2], float4 (&va)[2][4]) {
    const float* ksrc = Kb + (size_t)kb * 64 * 128;
    const float* vsrc = Vb + (size_t)kb * 64 * 128;
#pragma unroll
    for (int i = 0; i < 4; ++i) {
      const int task = tid + 256 * i;  // 1024 = 64 rows x 16 chunks(32B fp32)
      const float* p = ksrc + (task >> 4) * 128 + (task & 15) * 8;
      ka[i][0] = *(const float4*)p;
      ka[i][1] = *(const float4*)(p + 4);
    }
#pragma unroll
    for (int uu = 0; uu < 2; ++uu) {
      const int d0 = 4 * ((tid & 15) + 16 * uu);  // dim quad
      const int t0 = 4 * (tid >> 4);              // key quad 0..60
      const float* vr = vsrc + (size_t)t0 * 128 + d0;
#pragma unroll
      for (int j = 0; j < 4; ++j) va[uu][j] = *(const float4*)(vr + (size_t)j * 128);
    }
  };

  // ---- staging: convert + write regs into LDS buffer at byte offset bo
  auto writeKV = [&](int bo, const float4 (&ka)[4][2], const float4 (&va)[2][4]) {
    // K: row-major bf16, chunk-XOR swizzle (write side conflict-free)
#pragma unroll
    for (int i = 0; i < 4; ++i) {
      const int task = tid + 256 * i;
      const int r = task >> 4, c = task & 15;  // row 0..63, 16B-chunk 0..15
      const float4 a = ka[i][0], b2 = ka[i][1];
      u4v o = (u4v){pk2(a.x, a.y), pk2(a.z, a.w), pk2(b2.x, b2.y), pk2(b2.z, b2.w)};
      *(u4v*)(shc + bo + r * 256 + ((c * 16) ^ ((r & 7) << 4))) = o;
    }
    // V: 4x4 register transpose -> exact V^T slot-major layout (prepack port)
#pragma unroll
    for (int uu = 0; uu < 2; ++uu) {
      const int d0 = 4 * ((tid & 15) + 16 * uu);
      const int t0 = 4 * (tid >> 4);
      const float* f0 = (const float*)&va[uu][0];
      const float* f1 = (const float*)&va[uu][1];
      const float* f2 = (const float*)&va[uu][2];
      const float* f3 = (const float*)&va[uu][3];
      const int t32 = t0 >> 5, tt = t0 & 31;
      const int sl = tt >> 3, j0 = tt & 7;  // j0 in {0,4}
#pragma unroll
      for (int c = 0; c < 4; ++c) {
        const int d = d0 + c;
        *(u2v*)(shc + 32768 + bo + (t32 * 4096 + sl * 1024 + d * 8 + j0) * 2) =
            (u2v){pk2(f0[c], f1[c]), pk2(f2[c], f3[c])};
      }
    }
  };

  const int nkb = 2 * qt + 2;  // 64-key tiles, always even

  // ---- prologue: stage tile 0; Q-fragment conversion overlaps the loads
  float4 ka0[4][2], va0[2][4];
  loadKV(0, ka0, va0);

  const int qrow = qt * 128 + w * 32 + col;
  const float* qp = Qb + (size_t)qrow * 128;
  s8v qf[8];
#pragma unroll
  for (int ks = 0; ks < 8; ++ks) {
    const float4 x = *(const float4*)(qp + 16 * ks + 8 * hh);
    const float4 y = *(const float4*)(qp + 16 * ks + 8 * hh + 4);
    u4v q4 = (u4v){pk2(x.x * QS, x.y * QS), pk2(x.z * QS, x.w * QS),
                   pk2(y.x * QS, y.y * QS), pk2(y.z * QS, y.w * QS)};
    qf[ks] = __builtin_bit_cast(s8v, q4);
  }

  writeKV(0, ka0, va0);

  f16vf oacc[4];  // O^T: oacc[dblk][r] = Ou[q=col][d=32dblk+(r&3)+8(r>>2)+4hh]
#pragma unroll
  for (int i = 0; i < 4; ++i)
#pragma unroll
    for (int j = 0; j < 16; ++j) oacc[i][j] = 0.f;
  float l_i = 0.f;

  __syncthreads();  // tile 0 in LDS

  for (int kb = 0; kb < nkb; ++kb) {
    const int bo = (kb & 1) ? 16384 : 0;
    const bool more = (kb + 1 < nkb);

    // issue next tile's global loads NOW; they land during compute (T14)
    float4 ka[4][2], va[2][4];
    if (more) loadKV(kb + 1, ka, va);

    // ---- S^T - C for both 32-key subtiles, interleaved (independent chains)
    f16vf sTa, sTb;
#pragma unroll
    for (int j = 0; j < 16; ++j) { sTa[j] = -CREF; sTb[j] = -CREF; }
#pragma unroll
    for (int ks = 0; ks < 8; ++ks) {
      const int koff = (ks * 32 + hh * 16) ^ kswz;  // swizzled in-row chunk
      s8v kfa = *(const s8v*)(shc + bo + col * 256 + koff);
      s8v kfb = *(const s8v*)(shc + bo + 8192 + col * 256 + koff);
      sTa = __builtin_amdgcn_mfma_f32_32x32x16_bf16(kfa, qf[ks], sTa, 0, 0, 0);
      sTb = __builtin_amdgcn_mfma_f32_32x32x16_bf16(kfb, qf[ks], sTb, 0, 0, 0);
    }

    // ---- causal mask (last two 64-key tiles only)
    if (kb >= 2 * qt) {
#pragma unroll
      for (int j = 0; j < 16; ++j) {
        const int key = kb * 64 + (j & 3) + 8 * (j >> 2) + 4 * hh;
        if (key > qrow) sTa[j] = -1e30f;
        if (key + 32 > qrow) sTb[j] = -1e30f;
      }
    }

    // ---- p = exp2(s - C); pack; accumulate l (4 chains)
    unsigned int pa[8], pb[8];
    float s0 = 0.f, s1 = 0.f, s2 = 0.f, s3 = 0.f;
#pragma unroll
    for (int q = 0; q < 8; ++q) {
      const float a0 = __builtin_amdgcn_exp2f(sTa[2 * q]);
      const float a1 = __builtin_amdgcn_exp2f(sTa[2 * q + 1]);
      const float b0 = __builtin_amdgcn_exp2f(sTb[2 * q]);
      const float b1 = __builtin_amdgcn_exp2f(sTb[2 * q + 1]);
      pa[q] = pk2(a0, a1);
      pb[q] = pk2(b0, b1);
      if (q & 1) { s1 += a0 + a1; s3 += b0 + b1; }
      else       { s0 += a0 + a1; s2 += b0 + b1; }
    }
    l_i += (s0 + s1) + (s2 + s3);

    // ---- PV: P^T B-fragments via half-wave exchange; Ou^T += V^T P^T
#pragma unroll
    for (int sub = 0; sub < 2; ++sub) {
      const unsigned int* pd = sub ? pb : pa;
      const int vbo = 32768 + bo + sub * 8192;
#pragma unroll
      for (int ksp = 0; ksp < 2; ++ksp) {
        const int e4 = ksp * 4;
        const unsigned int own0 = h1 ? pd[e4 + 2] : pd[e4 + 0];
        const unsigned int own1 = h1 ? pd[e4 + 3] : pd[e4 + 1];
        const unsigned int snd0 = h1 ? pd[e4 + 0] : pd[e4 + 2];
        const unsigned int snd1 = h1 ? pd[e4 + 1] : pd[e4 + 3];
        const unsigned int rcv0 = (unsigned int)__shfl_xor((int)snd0, 32);
        const unsigned int rcv1 = (unsigned int)__shfl_xor((int)snd1, 32);
        u4v pw;
        pw[0] = h1 ? rcv0 : own0;
        pw[1] = h1 ? rcv1 : own1;
        pw[2] = h1 ? own0 : rcv0;
        pw[3] = h1 ? own1 : rcv1;
        s8v pf = __builtin_bit_cast(s8v, pw);
#pragma unroll
        for (int dblk = 0; dblk < 4; ++dblk) {
          s8v vf = *(const s8v*)(shc + vVb + (vbo + ksp * 4096 + dblk * 512));
          oacc[dblk] = __builtin_amdgcn_mfma_f32_32x32x16_bf16(vf, pf, oacc[dblk], 0, 0, 0);
        }
      }
    }

    // ---- stage tile kb+1 into the other buffer (dead tile kb-1's space)
    if (more) writeKV(bo ^ 16384, ka, va);
    __syncthreads();
  }

  // ---- epilogue: normalize, store fp32 directly
  const float lt = l_i + __shfl_xor(l_i, 32);
  const float inv = 1.0f / lt;
  float* op = Ob + (size_t)qrow * 128;
#pragma unroll
  for (int dblk = 0; dblk < 4; ++dblk)
#pragma unroll
    for (int gg = 0; gg < 4; ++gg) {
      float4 st;
      st.x = oacc[dblk][4 * gg + 0] * inv;
      st.y = oacc[dblk][4 * gg + 1] * inv;
      st.z = oacc[dblk][4 * gg + 2] * inv;
      st.w = oacc[dblk][4 * gg + 3] * inv;
      *(float4*)(op + dblk * 32 + 8 * gg + 4 * hh) = st;
    }
}

extern "C" void kernel_launch(void* const* d_in, const int* in_sizes, int n_in,
                              void* d_out, int out_size, void* d_ws, size_t ws_size,
                              hipStream_t stream) {
  const float* q = (const float*)d_in[0];
  const float* k = (const float*)d_in[1];
  const float* v = (const float*)d_in[2];
  float* o = (float*)d_out;
  (void)d_ws; (void)ws_size;  // fused kernel: no workspace, no prepack pass
  gqa_attn_kernel<<<dim3(512), dim3(256), 0, stream>>>(q, k, v, o);
}